// Round 1
// baseline (66.853 us; speedup 1.0000x reference)
//
#include <hip/hip_runtime.h>

// Conv2dLocal: spatially-varying depthwise 3x3 convolution.
// input:  [B, C, H, W]   fp32
// weight: [B, C*9, H, W] fp32 (tap t = i*3 + j, i=row offset, j=col offset)
// out:    [B, C, H, W]   fp32
// B=2, C=32, H=256, W=512 (all powers of two -> shifts/masks for indexing)

constexpr int Bc = 2;
constexpr int Cc = 32;
constexpr int Hc = 256;
constexpr int Wc = 512;
constexpr int W4 = Wc / 4;  // 128 float4-threads per row

__global__ __launch_bounds__(256) void conv2dlocal_kernel(
    const float* __restrict__ in,
    const float* __restrict__ wt,
    float* __restrict__ out)
{
    const int idx = blockIdx.x * blockDim.x + threadIdx.x;
    // idx enumerates (bc, h, wv) row-major: idx = (bc*H + h)*W4 + wv
    const int wv = idx & (W4 - 1);
    const int t1 = idx >> 7;          // / W4
    const int h  = t1 & (Hc - 1);
    const int bc = t1 >> 8;           // b*C + c
    const int w0 = wv << 2;

    const float* ip = in + (size_t)bc * Hc * Wc;

    // Load 3 input rows x 6 columns (w0-1 .. w0+4), zero-padded at borders.
    float v[3][6];
    #pragma unroll
    for (int r = 0; r < 3; ++r) {
        const int hh = h + r - 1;
        if (hh < 0 || hh >= Hc) {
            #pragma unroll
            for (int j = 0; j < 6; ++j) v[r][j] = 0.f;
        } else {
            const float* rp = ip + (size_t)hh * Wc + w0;
            const float4 c4 = *reinterpret_cast<const float4*>(rp);
            v[r][1] = c4.x; v[r][2] = c4.y; v[r][3] = c4.z; v[r][4] = c4.w;
            v[r][0] = (w0 > 0)      ? rp[-1] : 0.f;
            v[r][5] = (w0 + 4 < Wc) ? rp[4]  : 0.f;
        }
    }

    // 9 weight planes, each coalesced float4 read.
    float acc0 = 0.f, acc1 = 0.f, acc2 = 0.f, acc3 = 0.f;
    const float* wp = wt + ((size_t)bc * 9 * Hc + h) * Wc + w0;
    #pragma unroll
    for (int t = 0; t < 9; ++t) {
        const int r  = t / 3;
        const int cj = t % 3;
        const float4 w4 = *reinterpret_cast<const float4*>(wp + (size_t)t * Hc * Wc);
        acc0 = fmaf(w4.x, v[r][cj + 0], acc0);
        acc1 = fmaf(w4.y, v[r][cj + 1], acc1);
        acc2 = fmaf(w4.z, v[r][cj + 2], acc2);
        acc3 = fmaf(w4.w, v[r][cj + 3], acc3);
    }

    *reinterpret_cast<float4*>(out + (size_t)idx * 4) =
        make_float4(acc0, acc1, acc2, acc3);
}

extern "C" void kernel_launch(void* const* d_in, const int* in_sizes, int n_in,
                              void* d_out, int out_size, void* d_ws, size_t ws_size,
                              hipStream_t stream) {
    const float* in = (const float*)d_in[0];
    const float* wt = (const float*)d_in[1];
    float* out = (float*)d_out;

    const int total_threads = Bc * Cc * Hc * W4;   // 2*32*256*128 = 2,097,152
    const int block = 256;
    const int grid = total_threads / block;        // 8192
    conv2dlocal_kernel<<<grid, block, 0, stream>>>(in, wt, out);
}